// Round 1
// baseline (104.860 us; speedup 1.0000x reference)
//
#include <hip/hip_runtime.h>

#define N_FEAT 128
#define ROWS   32      // rows per LDS tile
#define TPB    256     // 4 waves; each wave computes 8 rows of the tile

// DPP cross-lane add on the VALU pipe: v + dpp_perm(v). No LDS traffic.
template<int CTRL>
__device__ __forceinline__ float dpp_xadd(float v) {
    int t = __builtin_amdgcn_update_dpp(0, __float_as_int(v), CTRL, 0xF, 0xF, true);
    return v + __int_as_float(t);
}

// Full 64-lane sum entirely on VALU (DPP + gfx950 permlane*_swap).
// Tree is bitwise-identical to the xor-butterfly (each stage adds the
// already-uniform partial of the partner half).
__device__ __forceinline__ float wave_allsum(float v) {
    v = dpp_xadd<0xB1>(v);    // quad_perm [1,0,3,2]  == xor 1
    v = dpp_xadd<0x4E>(v);    // quad_perm [2,3,0,1]  == xor 2
    v = dpp_xadd<0x141>(v);   // row_half_mirror      == xor 4 (quads uniform)
    v = dpp_xadd<0x140>(v);   // row_mirror           == xor 8 (octets uniform)
#if __has_builtin(__builtin_amdgcn_permlane16_swap)
    {   // rows(16) swap: out0={r0,r0,r2,r2}, out1={r1,r1,r3,r3} -> sum == xor 16
        auto p = __builtin_amdgcn_permlane16_swap(__float_as_uint(v), __float_as_uint(v), false, false);
        v = __uint_as_float(p[0]) + __uint_as_float(p[1]);
    }
#else
    v += __int_as_float(__builtin_amdgcn_ds_swizzle(__float_as_int(v), 0x401F)); // xor 16
#endif
    {   // half swap: out0={lo,lo}, out1={hi,hi} -> sum == xor 32
        auto p = __builtin_amdgcn_permlane32_swap(__float_as_uint(v), __float_as_uint(v), false, false);
        v = __uint_as_float(p[0]) + __uint_as_float(p[1]);
    }
    return v;
}

__global__ __launch_bounds__(TPB, 6)
void spn_fused(const float* __restrict__ x,
               const float* __restrict__ means,
               const float* __restrict__ stds,
               const float* __restrict__ sumw,
               const int* __restrict__ perm,
               float* __restrict__ out, int n) {
    __shared__ float sx[ROWS * N_FEAT];                    // 16 KB row tile, linear (global_load_lds dest)

    const float NHALF_LOG2E = -0.7213475204444817f;        // -0.5*log2(e)
    const float LN2     = 0.6931471805599453f;
    const float LOG2PI_ = 1.8378770664093453f;             // ln(2*pi)
    const float LOG2E   = 1.4426950408889634f;

    const int tid  = threadIdx.x;
    const int lane = tid & 63;
    const int wv   = tid >> 6;

    const int ntiles = n / ROWS;

    // async global->LDS staging: 16 chunks of 1 KB; wave wv takes chunks {wv,4+wv,8+wv,12+wv}.
    // LDS dest is wave-uniform base (+ lane*16 by HW); global src is per-lane.
    auto issue_tile = [&](int t) {
        const float* g0 = x + (size_t)t * (ROWS * N_FEAT);
#pragma unroll
        for (int it = 0; it < 4; ++it) {
            const int chunk = it * 4 + wv;
            __builtin_amdgcn_global_load_lds(
                (const __attribute__((address_space(1))) unsigned*)(g0 + chunk * 256 + lane * 4),
                (__attribute__((address_space(3))) unsigned*)(sx + chunk * 256),
                16, 0, 0);
        }
    };

    int tile  = blockIdx.x;
    bool have = tile < ntiles;
    if (have) issue_tile(tile);            // loads in flight while we fold params below

    // ---- per-lane param fold (each lane owns group g = lane; all waves redundant) ----
    // means/stds/sumw/perm are ~2.3 KB total -> L2-resident after first blocks.
    const int g  = lane;
    const int p0 = perm[2 * g], p1 = perm[2 * g + 1];
    const float w0 = sumw[g * 3 + 0], w1 = sumw[g * 3 + 1], w2 = sumw[g * 3 + 2];
    const float wmx = fmaxf(w0, fmaxf(w1, w2));
    const float lse = wmx + logf(expf(w0 - wmx) + expf(w1 - wmx) + expf(w2 - wmx));
    float nm0[3], is0[3], nm1[3], is1[3], C2[3];
#pragma unroll
    for (int m = 0; m < 3; ++m) {
        const float s0 = stds[p0 * 3 + m], mu0 = means[p0 * 3 + m];
        const float s1 = stds[p1 * 3 + m], mu1 = means[p1 * 3 + m];
        const float i0 = 1.0f / s0, i1 = 1.0f / s1;
        const float wm = (m == 0 ? w0 : (m == 1 ? w1 : w2));
        nm0[m] = mu0 * i0;  is0[m] = i0;
        nm1[m] = mu1 * i1;  is1[m] = i1;
        C2[m]  = ((wm - lse) - logf(s0) - logf(s1) - LOG2PI_) * LOG2E;
    }

    while (have) {
        __syncthreads();                   // drains vmcnt -> staged tile visible

        const int rowbase = tile * ROWS;
        float res[8];
#pragma unroll
        for (int r = 0; r < 8; ++r) {
            const float* xr = sx + (wv * 8 + r) * N_FEAT;
            const float a = xr[p0];
            const float b = xr[p1];
            float v0, v1, v2;
            {
                float z0 = fmaf(a, is0[0], -nm0[0]);
                float z1 = fmaf(b, is1[0], -nm1[0]);
                v0 = fmaf(z0 * z0, NHALF_LOG2E, C2[0]);
                v0 = fmaf(z1 * z1, NHALF_LOG2E, v0);
            }
            {
                float z0 = fmaf(a, is0[1], -nm0[1]);
                float z1 = fmaf(b, is1[1], -nm1[1]);
                v1 = fmaf(z0 * z0, NHALF_LOG2E, C2[1]);
                v1 = fmaf(z1 * z1, NHALF_LOG2E, v1);
            }
            {
                float z0 = fmaf(a, is0[2], -nm0[2]);
                float z1 = fmaf(b, is1[2], -nm1[2]);
                v2 = fmaf(z0 * z0, NHALF_LOG2E, C2[2]);
                v2 = fmaf(z1 * z1, NHALF_LOG2E, v2);
            }
            float pmx = fmaxf(v0, fmaxf(v1, v2));
            float s = __builtin_amdgcn_exp2f(v0 - pmx)
                    + __builtin_amdgcn_exp2f(v1 - pmx)
                    + __builtin_amdgcn_exp2f(v2 - pmx);
            res[r] = pmx + __builtin_amdgcn_logf(s);   // v_log_f32 = log2
        }

        // 8 independent VALU reduction chains (no ds_swizzle)
#pragma unroll
        for (int r = 0; r < 8; ++r)
            res[r] = wave_allsum(res[r]);

        const int next = tile + (int)gridDim.x;
        have = next < ntiles;
        if (have) {
            __syncthreads();               // all lanes done reading sx
            issue_tile(next);              // overlap next tile's loads with the store
        }

        if (lane == 0) {
            float4* op = (float4*)(out + rowbase + wv * 8);
            op[0] = make_float4(res[0] * LN2, res[1] * LN2, res[2] * LN2, res[3] * LN2);
            op[1] = make_float4(res[4] * LN2, res[5] * LN2, res[6] * LN2, res[7] * LN2);
        }
        tile = next;
    }
}

extern "C" void kernel_launch(void* const* d_in, const int* in_sizes, int n_in,
                              void* d_out, int out_size, void* d_ws, size_t ws_size,
                              hipStream_t stream) {
    const float* x     = (const float*)d_in[0];
    const float* means = (const float*)d_in[1];
    const float* stds  = (const float*)d_in[2];
    const float* sumw  = (const float*)d_in[3];
    const int*   perm  = (const int*)d_in[4];
    float* out = (float*)d_out;
    int n = in_sizes[0] / N_FEAT;          // 131072 rows

    int ntiles = n / ROWS;                 // 4096
    int grid = ntiles > 0 ? ntiles : 1;    // one tile per block; grid-stride covers overflow
    if (grid > 16384) grid = 16384;

    hipLaunchKernelGGL(spn_fused, dim3(grid), dim3(TPB), 0, stream,
                       x, means, stds, sumw, perm, out, n);
}

// Round 2
// 99.824 us; speedup vs baseline: 1.0505x; 1.0505x over previous
//
#include <hip/hip_runtime.h>

#define N_FEAT 128
#define ROWS   32      // rows per tile
#define TPB    256     // 4 waves; each wave owns 8 rows of the tile
#define GRID   1024    // 4 tiles per block (ntiles = 4096)

// counted vmcnt wait; memory clobber orders all memory ops across it
#define WAITV(N) asm volatile("s_waitcnt vmcnt(" #N ")" ::: "memory")

// DPP cross-lane add on the VALU pipe: v + dpp_perm(v). No LDS traffic.
template<int CTRL>
__device__ __forceinline__ float dpp_xadd(float v) {
    int t = __builtin_amdgcn_update_dpp(0, __float_as_int(v), CTRL, 0xF, 0xF, true);
    return v + __int_as_float(t);
}

// Full 64-lane sum entirely on VALU (DPP + gfx950 permlane*_swap).
__device__ __forceinline__ float wave_allsum(float v) {
    v = dpp_xadd<0xB1>(v);    // quad_perm [1,0,3,2]  == xor 1
    v = dpp_xadd<0x4E>(v);    // quad_perm [2,3,0,1]  == xor 2
    v = dpp_xadd<0x141>(v);   // row_half_mirror      == xor 4
    v = dpp_xadd<0x140>(v);   // row_mirror           == xor 8
#if __has_builtin(__builtin_amdgcn_permlane16_swap)
    {
        auto p = __builtin_amdgcn_permlane16_swap(__float_as_uint(v), __float_as_uint(v), false, false);
        v = __uint_as_float(p[0]) + __uint_as_float(p[1]);   // == xor 16
    }
#else
    v += __int_as_float(__builtin_amdgcn_ds_swizzle(__float_as_int(v), 0x401F));
#endif
    {
        auto p = __builtin_amdgcn_permlane32_swap(__float_as_uint(v), __float_as_uint(v), false, false);
        v = __uint_as_float(p[0]) + __uint_as_float(p[1]);   // == xor 32
    }
    return v;
}

__global__ __launch_bounds__(TPB, 4)
void spn_fused(const float* __restrict__ x,
               const float* __restrict__ means,
               const float* __restrict__ stds,
               const float* __restrict__ sumw,
               const int* __restrict__ perm,
               float* __restrict__ out, int n) {
    // 2 buffers x 4 waves x 1024 floats = 32 KB. Wave-private: NO __syncthreads anywhere.
    __shared__ float sx[2 * ROWS * N_FEAT];

    const float NHALF_LOG2E = -0.7213475204444817f;        // -0.5*log2(e)
    const float LN2      = 0.6931471805599453f;
    const float LOG2E    = 1.4426950408889634f;
    const float L2PI_L2E = 2.6514961294723187f;            // ln(2*pi)*log2(e)

    const int tid  = threadIdx.x;
    const int lane = tid & 63;
    const int wv   = tid >> 6;

    float* buf0 = sx + wv * (8 * N_FEAT);                  // this wave's buffer A (4 KB)
    float* buf1 = sx + 4 * (8 * N_FEAT) + wv * (8 * N_FEAT); // buffer B

    const int ntiles = n / ROWS;
    const int stride = gridDim.x;

    // stage THIS wave's 8 rows of tile t (4 KB) via 4x global_load_lds(16B)
    auto issue = [&](int t, float* dst) {
        const float* g0 = x + (size_t)t * (ROWS * N_FEAT) + wv * (8 * N_FEAT);
#pragma unroll
        for (int it = 0; it < 4; ++it) {
            __builtin_amdgcn_global_load_lds(
                (const __attribute__((address_space(1))) unsigned*)(g0 + it * 256 + lane * 4),
                (__attribute__((address_space(3))) unsigned*)(dst + it * 256),
                16, 0, 0);
        }
    };

    const int t0 = blockIdx.x;
    if (t0 < ntiles) issue(t0, buf0);      // start streaming before the fold

    // ---- per-lane param fold, log2-domain (v_log/v_exp only, no libm) ----
    const int g  = lane;
    const int p0 = perm[2 * g], p1 = perm[2 * g + 1];
    float w2[3];
#pragma unroll
    for (int m = 0; m < 3; ++m) w2[m] = sumw[g * 3 + m] * LOG2E;
    const float mx2 = fmaxf(w2[0], fmaxf(w2[1], w2[2]));
    const float lse2 = mx2 + __builtin_amdgcn_logf(__builtin_amdgcn_exp2f(w2[0] - mx2)
                                                 + __builtin_amdgcn_exp2f(w2[1] - mx2)
                                                 + __builtin_amdgcn_exp2f(w2[2] - mx2));
    float nm0[3], is0[3], nm1[3], is1[3], C2[3];
#pragma unroll
    for (int m = 0; m < 3; ++m) {
        const float s0 = stds[p0 * 3 + m], mu0 = means[p0 * 3 + m];
        const float s1 = stds[p1 * 3 + m], mu1 = means[p1 * 3 + m];
        const float i0 = 1.0f / s0, i1 = 1.0f / s1;
        nm0[m] = mu0 * i0;  is0[m] = i0;
        nm1[m] = mu1 * i1;  is1[m] = i1;
        C2[m]  = (w2[m] - lse2) - __builtin_amdgcn_logf(s0)
                                - __builtin_amdgcn_logf(s1) - L2PI_L2E;
    }

    WAITV(0);                              // tile t0 staged (also covers param loads)

    // ---- pipelined main loop: issue(t+stride) -> vmcnt(6) -> compute(t) -> store ----
    // Queue simulation (loads=4, stores=2 per iter): steady wait vmcnt(6) drains
    // exactly the current tile's loads; last iter vmcnt(2); never vmcnt(0) mid-loop.
    int k = 0;
    for (int t = t0; t < ntiles; t += stride, ++k) {
        float* cbuf = (k & 1) ? buf1 : buf0;
        const int tn = t + stride;
        if (tn < ntiles) {
            issue(tn, (k & 1) ? buf0 : buf1);
            WAITV(6);
        } else {
            WAITV(2);
        }

        float res[8];
#pragma unroll
        for (int r = 0; r < 8; ++r) {
            const float* xr = cbuf + r * N_FEAT;
            const float a = xr[p0];
            const float b = xr[p1];
            float v0, v1, v2;
            {
                float z0 = fmaf(a, is0[0], -nm0[0]);
                float z1 = fmaf(b, is1[0], -nm1[0]);
                v0 = fmaf(z0 * z0, NHALF_LOG2E, C2[0]);
                v0 = fmaf(z1 * z1, NHALF_LOG2E, v0);
            }
            {
                float z0 = fmaf(a, is0[1], -nm0[1]);
                float z1 = fmaf(b, is1[1], -nm1[1]);
                v1 = fmaf(z0 * z0, NHALF_LOG2E, C2[1]);
                v1 = fmaf(z1 * z1, NHALF_LOG2E, v1);
            }
            {
                float z0 = fmaf(a, is0[2], -nm0[2]);
                float z1 = fmaf(b, is1[2], -nm1[2]);
                v2 = fmaf(z0 * z0, NHALF_LOG2E, C2[2]);
                v2 = fmaf(z1 * z1, NHALF_LOG2E, v2);
            }
            float pmx = fmaxf(v0, fmaxf(v1, v2));
            float s = __builtin_amdgcn_exp2f(v0 - pmx)
                    + __builtin_amdgcn_exp2f(v1 - pmx)
                    + __builtin_amdgcn_exp2f(v2 - pmx);
            res[r] = pmx + __builtin_amdgcn_logf(s);   // v_log_f32 = log2
        }

        // 8 independent VALU reduction chains (zero DS-pipe traffic)
#pragma unroll
        for (int r = 0; r < 8; ++r)
            res[r] = wave_allsum(res[r]);

        if (lane == 0) {
            float4* op = (float4*)(out + t * ROWS + wv * 8);
            op[0] = make_float4(res[0] * LN2, res[1] * LN2, res[2] * LN2, res[3] * LN2);
            op[1] = make_float4(res[4] * LN2, res[5] * LN2, res[6] * LN2, res[7] * LN2);
        }
    }
}

extern "C" void kernel_launch(void* const* d_in, const int* in_sizes, int n_in,
                              void* d_out, int out_size, void* d_ws, size_t ws_size,
                              hipStream_t stream) {
    const float* x     = (const float*)d_in[0];
    const float* means = (const float*)d_in[1];
    const float* stds  = (const float*)d_in[2];
    const float* sumw  = (const float*)d_in[3];
    const int*   perm  = (const int*)d_in[4];
    float* out = (float*)d_out;
    int n = in_sizes[0] / N_FEAT;          // 131072 rows

    int ntiles = n / ROWS;                 // 4096
    int grid = GRID < ntiles ? GRID : (ntiles > 0 ? ntiles : 1);

    hipLaunchKernelGGL(spn_fused, dim3(grid), dim3(TPB), 0, stream,
                       x, means, stds, sumw, perm, out, n);
}